// Round 1
// baseline (103.361 us; speedup 1.0000x reference)
//
#include <hip/hip_runtime.h>

#define H 1024
#define NROWS 32768
#define NG 65536
#define NSEG 16384

#define BM 128
#define BN 128
#define BK 64

typedef __attribute__((ext_vector_type(8))) short bf16x8;
typedef __attribute__((ext_vector_type(4))) float f32x4;

__device__ __forceinline__ unsigned short f2bf(float x) {
    unsigned u = __builtin_bit_cast(unsigned, x);
    unsigned r = (u + 0x7fffu + ((u >> 16) & 1u)) >> 16;
    return (unsigned short)r;
}

__device__ __forceinline__ void gload_lds16(const void* g, void* l) {
    __builtin_amdgcn_global_load_lds(
        (const __attribute__((address_space(1))) void*)g,
        (__attribute__((address_space(3))) void*)l, 16, 0, 0);
}

// ---- Kernel 1: segment boundaries via binary search (segment_ids sorted) ----
__global__ void seg_bounds_kernel(const int* __restrict__ seg, int* __restrict__ seg_start) {
    int g = blockIdx.x * 256 + threadIdx.x;
    if (g > NSEG) return;
    if (g == NSEG) { seg_start[g] = NG; return; }
    int lo = 0, hi = NG;
    while (lo < hi) { int mid = (lo + hi) >> 1; if (seg[mid] < g) lo = mid + 1; else hi = mid; }
    seg_start[g] = lo;
}

// ---- Kernel 2: dense_w fp32 -> bf16 ----
__global__ void convert_w_kernel(const float* __restrict__ w, unsigned short* __restrict__ wbf) {
    int i = (blockIdx.x * 256 + threadIdx.x) * 4;
    float4 v = *(const float4*)(w + i);
    ushort4 o;
    o.x = f2bf(v.x); o.y = f2bf(v.y); o.z = f2bf(v.z); o.w = f2bf(v.w);
    *(ushort4*)(wbf + i) = o;
}

// ---- Kernel 3: out[g] = proj_b ----
__global__ void init_out_kernel(float* __restrict__ out, const float* __restrict__ proj_b) {
    int i = blockIdx.x * 256 + threadIdx.x;
    if (i < NSEG) out[i] = proj_b[0];
}

// ---- Kernel 4: gather + segment mean -> bf16 h [NSEG, H] ----
__global__ void seg_mean_kernel(const float* __restrict__ hidden,
                                const int* __restrict__ flat_indices,
                                const int* __restrict__ seg_start,
                                unsigned short* __restrict__ hbf) {
    int g = blockIdx.x;
    int t = threadIdx.x;  // 256 threads, 4 floats each
    int s = seg_start[g], e = seg_start[g + 1];
    float4 acc = {0.f, 0.f, 0.f, 0.f};
    for (int i = s; i < e; ++i) {
        int row = flat_indices[i];
        float4 v = *((const float4*)(hidden + (size_t)row * H) + t);
        acc.x += v.x; acc.y += v.y; acc.z += v.z; acc.w += v.w;
    }
    float scale = (e > s) ? 1.0f / (float)(e - s) : 0.0f;
    ushort4 o;
    o.x = f2bf(acc.x * scale); o.y = f2bf(acc.y * scale);
    o.z = f2bf(acc.z * scale); o.w = f2bf(acc.w * scale);
    *(ushort4*)(hbf + (size_t)g * H + t * 4) = o;
}

// ---- Kernel 5: bf16 MFMA GEMM [NSEG,H]x[H,H]^T fused gelu->proj epilogue ----
__global__ __launch_bounds__(256, 2) void gemm_kernel(
    const unsigned short* __restrict__ Abf,   // h bf16 [NSEG, H]
    const unsigned short* __restrict__ Wbf,   // dense_w bf16 [H, H] (row j contiguous in k)
    const float* __restrict__ dense_b,
    const float* __restrict__ proj_w,
    float* __restrict__ out) {
    __shared__ unsigned short As[BM * BK];
    __shared__ unsigned short Bs[BN * BK];
    const int tid = threadIdx.x;
    const int wid = tid >> 6, lane = tid & 63;
    const int wr = wid >> 1, wc = wid & 1;
    const int m0 = blockIdx.x * BM, n0 = blockIdx.y * BN;

    f32x4 acc[4][4] = {};

    for (int kt = 0; kt < H / BK; ++kt) {
        // Stage A (16KB) + B (16KB): linear LDS dest, pre-swizzled global source.
        // LDS row stride = 128B; read-side XOR swizzle = ((row&7)<<4).
#pragma unroll
        for (int it = 0; it < 4; ++it) {
            int c = it * 256 + tid;          // 16B chunk index, 0..1023
            int row = c >> 3;                // tile row
            int sw = ((c & 7) << 4) ^ ((row & 7) << 4);
            gload_lds16((const char*)Abf + (((size_t)(m0 + row)) << 11) + kt * 128 + sw,
                        (char*)As + (it * 256 + wid * 64) * 16);
            gload_lds16((const char*)Wbf + (((size_t)(n0 + row)) << 11) + kt * 128 + sw,
                        (char*)Bs + (it * 256 + wid * 64) * 16);
        }
        __syncthreads();
#pragma unroll
        for (int kk = 0; kk < 2; ++kk) {
            bf16x8 af[4], bfr[4];
            int kb = kk * 64 + ((lane >> 4) << 4);
#pragma unroll
            for (int mi = 0; mi < 4; ++mi) {
                int row = wr * 64 + mi * 16 + (lane & 15);
                af[mi] = *(const bf16x8*)((const char*)As + row * 128 + (kb ^ ((row & 7) << 4)));
            }
#pragma unroll
            for (int ni = 0; ni < 4; ++ni) {
                int row = wc * 64 + ni * 16 + (lane & 15);
                bfr[ni] = *(const bf16x8*)((const char*)Bs + row * 128 + (kb ^ ((row & 7) << 4)));
            }
#pragma unroll
            for (int mi = 0; mi < 4; ++mi)
#pragma unroll
                for (int ni = 0; ni < 4; ++ni)
                    acc[mi][ni] = __builtin_amdgcn_mfma_f32_16x16x32_bf16(af[mi], bfr[ni], acc[mi][ni], 0, 0, 0);
        }
        __syncthreads();
    }

    // Epilogue: z = gelu(acc + b[n]); contribution = z * proj_w[n]; reduce over n.
#pragma unroll
    for (int mi = 0; mi < 4; ++mi) {
#pragma unroll
        for (int r = 0; r < 4; ++r) {
            int m = m0 + wr * 64 + mi * 16 + ((lane >> 4) << 2) + r;
            float s = 0.f;
#pragma unroll
            for (int ni = 0; ni < 4; ++ni) {
                int n = n0 + wc * 64 + ni * 16 + (lane & 15);
                float z = acc[mi][ni][r] + dense_b[n];
                float gl = 0.5f * z * (1.0f + erff(z * 0.70710678118f));
                s += gl * proj_w[n];
            }
#pragma unroll
            for (int off = 1; off < 16; off <<= 1) s += __shfl_xor(s, off, 64);
            if ((lane & 15) == 0) atomicAdd(out + m, s);
        }
    }
}

extern "C" void kernel_launch(void* const* d_in, const int* in_sizes, int n_in,
                              void* d_out, int out_size, void* d_ws, size_t ws_size,
                              hipStream_t stream) {
    const float* hidden       = (const float*)d_in[0];
    const float* dense_w      = (const float*)d_in[1];
    const float* dense_b      = (const float*)d_in[2];
    const float* proj_w       = (const float*)d_in[3];
    const float* proj_b       = (const float*)d_in[4];
    const int*   flat_indices = (const int*)d_in[5];
    const int*   segment_ids  = (const int*)d_in[6];
    float* out = (float*)d_out;

    char* ws = (char*)d_ws;
    int* seg_start = (int*)ws;                                   // 16385 ints (~64KB)
    unsigned short* hbf = (unsigned short*)(ws + (1 << 17));     // 32MB
    unsigned short* wbf = (unsigned short*)(ws + (1 << 17) + (size_t)NSEG * H * 2);  // 2MB

    hipLaunchKernelGGL(seg_bounds_kernel, dim3(65), dim3(256), 0, stream, segment_ids, seg_start);
    hipLaunchKernelGGL(convert_w_kernel, dim3(H * H / 1024), dim3(256), 0, stream, dense_w, wbf);
    hipLaunchKernelGGL(init_out_kernel, dim3(64), dim3(256), 0, stream, out, proj_b);
    hipLaunchKernelGGL(seg_mean_kernel, dim3(NSEG), dim3(256), 0, stream, hidden, flat_indices, seg_start, hbf);
    hipLaunchKernelGGL(gemm_kernel, dim3(NSEG / BM, H / BN), dim3(256), 0, stream, hbf, wbf, dense_b, proj_w, out);
}